// Round 5
// baseline (263.118 us; speedup 1.0000x reference)
//
#include <hip/hip_runtime.h>
#include <stdint.h>

#define NB 4           // batches
#define M 5000         // boxes per batch
#define KOUT 2000      // output rois per batch
#define MP 5120        // padded M (multiple of 128)
#define NT 40          // tiles of 128 over MP
#define NTP 820        // NT*(NT+1)/2 upper-tri tile pairs
#define NTASK (NB*NTP) // 3280 tile-pair tasks
#define PAIR_CAP 8192  // per-batch pair capacity (global buffer)
#define SCAP 2048      // pairs staged in LDS for phase C (n ~100 expected)

#define GRID 800       // co-resident: capacity >= 1024 blocks (LDS 7/CU, thr 8/CU, VGPR>=4/CU)
#define IPB 25         // i's per block in phase A
#define NBI 200        // phase-A blocks per batch (NBI*IPB == M exactly)

// shared-memory union (21.5 KB static):
// A: ss[5000] f32 @0, part[256] i32 @20032
// B: abox[128] f4 @0, aA[128] @2048, bbox[128] f4 @2560, aB[128] @4608
// C: pk[2048] u32 @0, sup[5120] u8 @8192, nsup[5120] u8 @13312,
//    wsum[4] @18432, woff[4] @18448, chflag @18464
#define SMEM_BYTES 21504

__device__ inline void gsync(unsigned* bar, unsigned target) {
    __syncthreads();
    if (threadIdx.x == 0) {
        __threadfence();  // release our global writes (agent scope)
        __hip_atomic_fetch_add(bar, 1u, __ATOMIC_ACQ_REL, __HIP_MEMORY_SCOPE_AGENT);
        while (__hip_atomic_load(bar, __ATOMIC_ACQUIRE, __HIP_MEMORY_SCOPE_AGENT) < target)
            __builtin_amdgcn_s_sleep(8);
        __threadfence();
    }
    __syncthreads();
}

__global__ __launch_bounds__(64) void k_init(unsigned* __restrict__ cnt) {
    cnt[threadIdx.x] = 0u;   // zeroes cnt[0..3] and the barrier at cnt[32]
}

__global__ __launch_bounds__(256, 4) void k_fused(
    const float* __restrict__ boxes, const float* __restrict__ scores,
    float* __restrict__ sx1, float* __restrict__ sy1,
    float* __restrict__ sx2, float* __restrict__ sy2,
    unsigned* __restrict__ cnt, unsigned* __restrict__ pairs,
    float* __restrict__ out)
{
    __shared__ __align__(16) char smem[SMEM_BYTES];
    const int blk = blockIdx.x;
    const int t = threadIdx.x;
    unsigned* bar = cnt + 32;

    // ================= Phase A: stable rank sort by -score =================
    // rank(i) = #{j<i: s_j >= s_i} + #{j>i: s_j > s_i}  (exact stable argsort(-s))
    {
        float* ss = (float*)smem;
        int* part = (int*)(smem + 20032);
        const int b = blk / NBI;
        const int ic = blk - b * NBI;

        for (int j = t; j < M; j += 256) ss[j] = scores[b * M + j];
        __syncthreads();

        const int isub = t / 10;          // 0..25
        const int q = t - isub * 10;      // 10-way j-split
        int r = 0;
        if (t < 250) {
            const int i = ic * IPB + isub;    // < 5000 always
            const float si = ss[i];
            const float4* ss4 = (const float4*)ss;
            #pragma unroll 5
            for (int c = q; c < 1250; c += 10) {  // 10 addrs/wave: 2-way bank alias, free
                float4 v = ss4[c];
                int j = 4 * c;
                r += (j + 0 < i) ? (v.x >= si) : (v.x > si);
                r += (j + 1 < i) ? (v.y >= si) : (v.y > si);
                r += (j + 2 < i) ? (v.z >= si) : (v.z > si);
                r += (j + 3 < i) ? (v.w >= si) : (v.w > si);
            }
        }
        part[t] = r;
        __syncthreads();

        if (t < IPB) {
            int rank = 0;
            #pragma unroll
            for (int qq = 0; qq < 10; ++qq) rank += part[t * 10 + qq];
            const int i = ic * IPB + t;
            float4 bx = ((const float4*)boxes)[b * M + i];
            sx1[b * MP + rank] = bx.x;
            sy1[b * MP + rank] = bx.y;
            sx2[b * MP + rank] = bx.z;
            sy2[b * MP + rank] = bx.w;
        }
        if (ic == 0 && t < (MP - M)) {
            // far-away sentinel rows: never pair with real boxes (gj<M guard)
            int rr = M + t;
            sx1[b * MP + rr] = 3.0e9f;
            sy1[b * MP + rr] = 3.0e9f;
            sx2[b * MP + rr] = 3.0e9f;
            sy2[b * MP + rr] = 3.0e9f;
        }
    }
    gsync(bar, GRID);

    // ================= Phase B: sparse suppression-pair detection =================
    {
        float4* abox = (float4*)smem;
        float*  aA   = (float*)(smem + 2048);
        float4* bbox = (float4*)(smem + 2560);
        float*  aB   = (float*)(smem + 4608);

        for (int task = blk; task < NTASK; task += GRID) {
            const int b = task / NTP;
            int rem = task - b * NTP;
            int ti = 0;
            while (rem >= NT - ti) { rem -= NT - ti; ++ti; }
            const int tj = ti + rem;

            if (t < 128) {
                int g = ti * 128 + t;
                float x1 = sx1[b*MP+g], y1 = sy1[b*MP+g];
                float x2 = sx2[b*MP+g], y2 = sy2[b*MP+g];
                abox[t] = make_float4(x1, y1, x2, y2);
                aA[t] = __fmul_rn(__fadd_rn(__fsub_rn(x2,x1),1.0f),
                                  __fadd_rn(__fsub_rn(y2,y1),1.0f));
            } else {
                int tt = t - 128;
                int g = tj * 128 + tt;
                float x1 = sx1[b*MP+g], y1 = sy1[b*MP+g];
                float x2 = sx2[b*MP+g], y2 = sy2[b*MP+g];
                bbox[tt] = make_float4(x1, y1, x2, y2);
                aB[tt] = __fmul_rn(__fadd_rn(__fsub_rn(x2,x1),1.0f),
                                   __fadd_rn(__fsub_rn(y2,y1),1.0f));
            }
            __syncthreads();

            const int jj = t & 127;
            const int gj = tj * 128 + jj;
            if (gj < M) {   // kills all sentinel pairs too (gi<gj<M)
                const float4 qb = bbox[jj];
                const float qa = aB[jj];
                for (int ii = (t >> 7); ii < 128; ii += 2) {
                    int gi = ti * 128 + ii;
                    if (gi >= gj) continue;
                    float4 av = abox[ii];
                    float xx1 = fmaxf(av.x, qb.x);
                    float yy1 = fmaxf(av.y, qb.y);
                    float xx2 = fminf(av.z, qb.z);
                    float yy2 = fminf(av.w, qb.w);
                    float w = __fadd_rn(__fsub_rn(xx2, xx1), 1.0f);
                    float h = __fadd_rn(__fsub_rn(yy2, yy1), 1.0f);
                    if (w > 0.0f && h > 0.0f) {
                        float inter = __fmul_rn(w, h);
                        float uni = __fsub_rn(__fadd_rn(aA[ii], qa), inter);
                        float iou = __fdiv_rn(inter, uni);
                        if (iou > 0.7f) {
                            unsigned pos = atomicAdd(&cnt[b], 1u);
                            if (pos < PAIR_CAP)
                                pairs[b * PAIR_CAP + pos] = ((unsigned)gi << 13) | (unsigned)gj;
                        }
                    }
                }
            }
            __syncthreads();  // protect LDS tiles before restage
        }
    }
    gsync(bar, 2u * GRID);

    // ================= Phase C: Jacobi fixpoint + output (blocks 0..3) =================
    if (blk < NB) {
        const int b = blk;
        unsigned* pk = (unsigned*)smem;
        unsigned char* sup  = (unsigned char*)(smem + 8192);
        unsigned char* nsup = (unsigned char*)(smem + 13312);
        int* wsum   = (int*)(smem + 18432);
        int* woff   = (int*)(smem + 18448);
        int* chflag = (int*)(smem + 18464);

        int n = (int)cnt[b];
        if (n > PAIR_CAP) n = PAIR_CAP;
        const int ns = (n < SCAP) ? n : SCAP;
        for (int e = t; e < ns; e += 256) pk[e] = pairs[b * PAIR_CAP + e];
        for (int e = t; e < MP; e += 256) sup[e] = 0;
        __syncthreads();

        // sup[j] = OR over pairs (i,j) of !sup[i]; i<j strictly => DAG => unique fixpoint
        for (int round = 0; round < n + 2; ++round) {
            for (int e = t; e < MP; e += 256) nsup[e] = 0;
            if (t == 0) *chflag = 0;
            __syncthreads();
            for (int e = t; e < n; e += 256) {
                unsigned v = (e < SCAP) ? pk[e] : pairs[b * PAIR_CAP + e];
                int i = (int)(v >> 13);
                int j = (int)(v & 8191u);
                if (!sup[i]) nsup[j] = 1;   // benign race: all write 1
            }
            __syncthreads();
            int ch = 0;
            for (int e = t; e < MP; e += 256) {
                unsigned char nv = nsup[e];
                if (nv != sup[e]) { sup[e] = nv; ch = 1; }
            }
            if (ch) *chflag = 1;
            __syncthreads();
            int done = (*chflag == 0);
            __syncthreads();
            if (done) break;
        }

        // prefix sum of keep = !sup: 20 entries/thread -> wave scan -> 4-wave combine
        const int base = t * 20;
        int kp[20];
        int s = 0;
        #pragma unroll
        for (int qq = 0; qq < 20; ++qq) {
            int r = base + qq;
            kp[qq] = (r < M) ? (sup[r] ? 0 : 1) : 0;
            s += kp[qq];
        }
        const int lane = t & 63;
        const int w = t >> 6;
        int sc = s;
        #pragma unroll
        for (int d = 1; d < 64; d <<= 1) {
            int v = __shfl_up(sc, d, 64);
            if (lane >= d) sc += v;
        }
        if (lane == 63) wsum[w] = sc;
        __syncthreads();
        if (t == 0) {
            int acc = 0;
            #pragma unroll
            for (int ww = 0; ww < 4; ++ww) { woff[ww] = acc; acc += wsum[ww]; }
        }
        __syncthreads();
        const int excl = woff[w] + (sc - s);
        const int total = woff[3] + wsum[3];

        int pos = excl;
        #pragma unroll
        for (int qq = 0; qq < 20; ++qq) {
            int r = base + qq;
            if (kp[qq] && pos < KOUT) {
                float* o = out + ((size_t)(b * KOUT + pos)) * 5;
                o[0] = (float)b;
                o[1] = sx1[b * MP + r];
                o[2] = sy1[b * MP + r];
                o[3] = sx2[b * MP + r];
                o[4] = sy2[b * MP + r];
            }
            pos += kp[qq];
        }

        int kc = total; if (kc > KOUT) kc = KOUT;
        for (int e = kc * 5 + t; e < KOUT * 5; e += 256)
            out[(size_t)b * KOUT * 5 + e] = 0.0f;

        if (b == 0 && t == 0) {
            out[(size_t)NB * KOUT * 5 + 0] = 0.0f;
            out[(size_t)NB * KOUT * 5 + 1] = 0.0f;
        }
    }
}

extern "C" void kernel_launch(void* const* d_in, const int* in_sizes, int n_in,
                              void* d_out, int out_size, void* d_ws, size_t ws_size,
                              hipStream_t stream) {
    (void)in_sizes; (void)n_in; (void)out_size; (void)ws_size;
    const float* boxes  = (const float*)d_in[0];
    const float* scores = (const float*)d_in[1];
    float* out = (float*)d_out;

    // ws: 4 SoA coord arrays [NB*MP] + cnt[64] (cnt[0..3]=counters, cnt[32]=barrier) + pairs
    float* sx1 = (float*)d_ws;
    float* sy1 = sx1 + NB * MP;
    float* sx2 = sy1 + NB * MP;
    float* sy2 = sx2 + NB * MP;
    unsigned* cnt   = (unsigned*)(sy2 + NB * MP);
    unsigned* pairs = cnt + 64;

    hipLaunchKernelGGL(k_init,  dim3(1),    dim3(64),  0, stream, cnt);
    hipLaunchKernelGGL(k_fused, dim3(GRID), dim3(256), 0, stream,
                       boxes, scores, sx1, sy1, sx2, sy2, cnt, pairs, out);
}